// Round 3
// baseline (199.492 us; speedup 1.0000x reference)
//
#include <hip/hip_runtime.h>
#include <hip/hip_bf16.h>

typedef __attribute__((ext_vector_type(4))) float        f32x4;
typedef __attribute__((ext_vector_type(8))) short        s16x8;
typedef __attribute__((ext_vector_type(4))) unsigned int u32x4;
typedef __attribute__((ext_vector_type(2))) unsigned int u32x2;

#define Bb 8
#define Tt 1024
#define Ss 1024
#define Dd 2048
#define BM 128
#define BN 128
#define BK 64   // K-slab: 2 ks-steps of 32, 32 MFMA/wave/slab

// round-half-up f32 -> bf16, packed pair. Inputs are finite N(0,1); no NaN/Inf path.
__device__ __forceinline__ unsigned pack2_bf16(float f0, float f1) {
  unsigned u0 = __builtin_bit_cast(unsigned, f0) + 0x8000u;
  unsigned u1 = __builtin_bit_cast(unsigned, f1) + 0x8000u;
  return (u0 >> 16) | (u1 & 0xffff0000u);
}

// async global->LDS DMA, 16B/lane. LDS dest = wave-uniform base + lane*16.
__device__ __forceinline__ void gld_lds16(const void* g, void* l) {
  __builtin_amdgcn_global_load_lds(
      (__attribute__((address_space(1))) void*)(void*)(g),
      (__attribute__((address_space(3))) void*)l, 16, 0, 0);
}

// ---------------- Pass 1a: X_hats fp32 -> bf16 + inv-norms (HOIST+FENCE variant) ----
// A/B experiment arm A. 2 rows/wave, all 16 loads issued before any use, pinned
// with an IR-level memory fence (asm "memory") + sched_barrier(0). Verdict read:
// VGPR>=90 & dur<27us  -> hoist works, latency theory confirmed.
// VGPR<=48 & dur ~30us -> hoist defeated again, abandon this line.
__global__ __launch_bounds__(256, 4)
void convertA_kernel(const float* __restrict__ xh,
                     unsigned* __restrict__ abf, float* __restrict__ invA)
{
  const int wave = threadIdx.x >> 6, lane = threadIdx.x & 63;
  const int row = (blockIdx.x * 4 + wave) * 2;   // 1024 blocks * 8 rows = 8192

  const f32x4* s0 = (const f32x4*)(xh + (size_t)row * Dd);
  const f32x4* s1 = (const f32x4*)(xh + (size_t)(row + 1) * Dd);

  f32x4 v0[8], v1[8];
  #pragma unroll
  for (int j = 0; j < 8; ++j) v0[j] = s0[j * 64 + lane];
  #pragma unroll
  for (int j = 0; j < 8; ++j) v1[j] = s1[j * 64 + lane];
  asm volatile("" ::: "memory");          // IR-level: loads may not sink past here
  __builtin_amdgcn_sched_barrier(0);      // scheduler-level pin

  u32x2* d0 = (u32x2*)(abf + (size_t)row * (Dd / 2));
  u32x2* d1 = (u32x2*)(abf + (size_t)(row + 1) * (Dd / 2));
  float sq0 = 0.0f, sq1 = 0.0f;
  #pragma unroll
  for (int j = 0; j < 8; ++j) {
    f32x4 a = v0[j];
    sq0 = fmaf(a[0], a[0], fmaf(a[1], a[1], fmaf(a[2], a[2], fmaf(a[3], a[3], sq0))));
    d0[j * 64 + lane] = (u32x2){pack2_bf16(a[0], a[1]), pack2_bf16(a[2], a[3])};
  }
  #pragma unroll
  for (int j = 0; j < 8; ++j) {
    f32x4 a = v1[j];
    sq1 = fmaf(a[0], a[0], fmaf(a[1], a[1], fmaf(a[2], a[2], fmaf(a[3], a[3], sq1))));
    d1[j * 64 + lane] = (u32x2){pack2_bf16(a[0], a[1]), pack2_bf16(a[2], a[3])};
  }

  #pragma unroll
  for (int m = 32; m; m >>= 1) { sq0 += __shfl_xor(sq0, m, 64); sq1 += __shfl_xor(sq1, m, 64); }
  if (lane == 0) { invA[row] = 1.0f / sqrtf(sq0); invA[row + 1] = 1.0f / sqrtf(sq1); }
}

// ---------------- Pass 1b: support fp32 -> bf16 + inv-norms (HIGH-TLP variant) ----
// A/B experiment arm B. Block-per-row: 8192 blocks, 256 thr; thread t owns floats
// [t*8, t*8+8): two independent 16B loads, one 16B store, 8 fma; LDS reduce for
// the row norm. Short dependence chains + max TLP.
__global__ __launch_bounds__(256, 8)
void convertB_kernel(const float* __restrict__ sup,
                     unsigned* __restrict__ bbf, float* __restrict__ invB)
{
  __shared__ float red[4];
  const int row = blockIdx.x;              // 8192
  const int t = threadIdx.x;               // 0..255
  const f32x4* s = (const f32x4*)(sup + (size_t)row * Dd);
  const f32x4 a = s[2 * t];
  const f32x4 b = s[2 * t + 1];

  float sq = fmaf(a[0], a[0], fmaf(a[1], a[1], fmaf(a[2], a[2], a[3] * a[3])));
  sq = fmaf(b[0], b[0], fmaf(b[1], b[1], fmaf(b[2], b[2], fmaf(b[3], b[3], sq))));

  ((u32x4*)(bbf + (size_t)row * (Dd / 2)))[t] =
      (u32x4){pack2_bf16(a[0], a[1]), pack2_bf16(a[2], a[3]),
              pack2_bf16(b[0], b[1]), pack2_bf16(b[2], b[3])};

  #pragma unroll
  for (int m = 32; m; m >>= 1) sq += __shfl_xor(sq, m, 64);
  const int wave = t >> 6, lane = t & 63;
  if (lane == 0) red[wave] = sq;
  __syncthreads();
  if (t == 0) invB[row] = 1.0f / sqrtf(red[0] + red[1] + red[2] + red[3]);
}

// ---------------- Pass 2: bf16 GEMM, DMA staging, BK=64, double-buffered ----------------
// UNCHANGED from round 2 (so its counters, finally visible in top-5, are clean).
// T1 XCD swizzle: grid=512=8*64 bijective, XCD x <- batch x.
// LDS tiles 128x64 bf16, x2 buffers = 64KB. XOR swizzle on 16B chunks.
__global__ __launch_bounds__(256, 2)
void gemm_kernel(const short* __restrict__ abf, const short* __restrict__ bbf,
                 const float* __restrict__ invA, const float* __restrict__ invB,
                 float* __restrict__ out)
{
  __shared__ short As[2][BM * BK];   // 2 x 16 KB
  __shared__ short Bs[2][BN * BK];   // 2 x 16 KB

  const int bid0 = blockIdx.x;
  const int bid  = ((bid0 & 7) << 6) | (bid0 >> 3);   // T1: XCD-contiguous remap
  const int b    = bid >> 6;
  const int tile = bid & 63;
  const int tm   = tile >> 3;
  const int tn   = tile & 7;

  const int t = threadIdx.x, wave = t >> 6, lane = t & 63;

  const int srow = lane >> 3;
  const int cph  = lane & 7;
  const int r0   = wave * 32;

  const size_t aRow = (size_t)(b * Tt + tm * BM);
  const size_t bRow = (size_t)(b * Ss + tn * BN);
  const short *gA0, *gA1, *gA2, *gA3, *gB0, *gB1, *gB2, *gB3;
  {
    int r;
    r = r0 + 0 * 8 + srow; gA0 = abf + (aRow + r) * Dd + (cph ^ (r & 7)) * 8;
                           gB0 = bbf + (bRow + r) * Dd + (cph ^ (r & 7)) * 8;
    r = r0 + 1 * 8 + srow; gA1 = abf + (aRow + r) * Dd + (cph ^ (r & 7)) * 8;
                           gB1 = bbf + (bRow + r) * Dd + (cph ^ (r & 7)) * 8;
    r = r0 + 2 * 8 + srow; gA2 = abf + (aRow + r) * Dd + (cph ^ (r & 7)) * 8;
                           gB2 = bbf + (bRow + r) * Dd + (cph ^ (r & 7)) * 8;
    r = r0 + 3 * 8 + srow; gA3 = abf + (aRow + r) * Dd + (cph ^ (r & 7)) * 8;
                           gB3 = bbf + (bRow + r) * Dd + (cph ^ (r & 7)) * 8;
  }

  const int wm = (wave >> 1) << 6;
  const int wn = (wave & 1) << 6;
  const int lm = lane & 15;
  const int kq = lane >> 4;

  f32x4 acc[4][4];
  #pragma unroll
  for (int i = 0; i < 4; ++i)
    #pragma unroll
    for (int j = 0; j < 4; ++j)
      acc[i][j] = (f32x4)0.0f;

#define STAGE(bi) do {                                                   \
    gld_lds16(gA0, As[bi] + (r0 + 0)  * BK);                             \
    gld_lds16(gA1, As[bi] + (r0 + 8)  * BK);                             \
    gld_lds16(gA2, As[bi] + (r0 + 16) * BK);                             \
    gld_lds16(gA3, As[bi] + (r0 + 24) * BK);                             \
    gld_lds16(gB0, Bs[bi] + (r0 + 0)  * BK);                             \
    gld_lds16(gB1, Bs[bi] + (r0 + 8)  * BK);                             \
    gld_lds16(gB2, Bs[bi] + (r0 + 16) * BK);                             \
    gld_lds16(gB3, Bs[bi] + (r0 + 24) * BK);                             \
    gA0 += BK; gA1 += BK; gA2 += BK; gA3 += BK;                          \
    gB0 += BK; gB1 += BK; gB2 += BK; gB3 += BK;                          \
  } while (0)

#define COMPUTE(bi) do {                                                 \
    _Pragma("unroll")                                                    \
    for (int ks = 0; ks < 2; ++ks) {                                     \
      const int pchunk = ((ks * 4 + kq) ^ (lm & 7)) * 8;                 \
      s16x8 af[4], bfr[4];                                               \
      _Pragma("unroll")                                                  \
      for (int i = 0; i < 4; ++i) {                                      \
        af[i]  = *(const s16x8*)(As[bi] + (wm + i * 16 + lm) * BK + pchunk); \
        bfr[i] = *(const s16x8*)(Bs[bi] + (wn + i * 16 + lm) * BK + pchunk); \
      }                                                                  \
      _Pragma("unroll")                                                  \
      for (int mi = 0; mi < 4; ++mi)                                     \
        _Pragma("unroll")                                                \
        for (int ni = 0; ni < 4; ++ni)                                   \
          acc[mi][ni] = __builtin_amdgcn_mfma_f32_16x16x32_bf16(af[mi], bfr[ni], acc[mi][ni], 0, 0, 0); \
    }                                                                    \
  } while (0)

  STAGE(0);
  __syncthreads();

  for (int k0 = 0; k0 < Dd; k0 += 2 * BK) {
    STAGE(1);
    COMPUTE(0);
    __syncthreads();
    if (k0 + 2 * BK < Dd) STAGE(0);
    COMPUTE(1);
    __syncthreads();
  }
#undef STAGE
#undef COMPUTE

  const float* iA = invA + b * Tt + tm * BM;
  const float* iB = invB + b * Ss + tn * BN;
  float* outb = out + (size_t)(b * Tt + tm * BM) * Ss + tn * BN;
  const int m0 = wm + kq * 4;
  const int n0 = wn + lm;
  #pragma unroll
  for (int mi = 0; mi < 4; ++mi) {
    #pragma unroll
    for (int r = 0; r < 4; ++r) {
      const int mrow = m0 + mi * 16 + r;
      const float ia = iA[mrow];
      float* orow = outb + (size_t)mrow * Ss;
      #pragma unroll
      for (int ni = 0; ni < 4; ++ni) {
        const int ncol = n0 + ni * 16;
        orow[ncol] = acc[mi][ni][r] * (ia * iB[ncol]);
      }
    }
  }
}

// ---------------- Fallback: round-1 fused kernel (used only if ws too small) ----------------
#define LDKF 40
#define BKF 32
__global__ __launch_bounds__(256, 2)
void paircos_kernel(const float* __restrict__ sup, const float* __restrict__ xh,
                    float* __restrict__ out)
{
  __shared__ short As[BM * LDKF];
  __shared__ short Bs[BN * LDKF];
  __shared__ float invA[BM];
  __shared__ float invB[BN];

  const int bid = blockIdx.x;
  const int b = bid >> 6, tile = bid & 63, tm = tile >> 3, tn = tile & 7;
  const float* Abase = xh  + (size_t)(b * Tt + tm * BM) * Dd;
  const float* Bbase = sup + (size_t)(b * Ss + tn * BN) * Dd;
  const int t = threadIdx.x, row = t >> 1, kh = t & 1;
  const f32x4* agp = (const f32x4*)(Abase + (size_t)row * Dd + kh * 16);
  const f32x4* bgp = (const f32x4*)(Bbase + (size_t)row * Dd + kh * 16);
  u32x4* awr = (u32x4*)(As + row * LDKF + kh * 16);
  u32x4* bwr = (u32x4*)(Bs + row * LDKF + kh * 16);
  const int wave = t >> 6, lane = t & 63;
  const int wm = (wave >> 1) << 6, wn = (wave & 1) << 6;
  const int lm = lane & 15, kq = lane >> 4;

  f32x4 acc[4][4];
  #pragma unroll
  for (int i = 0; i < 4; ++i)
    #pragma unroll
    for (int j = 0; j < 4; ++j) acc[i][j] = (f32x4)0.0f;
  float sqa = 0.0f, sqb = 0.0f;
  f32x4 areg[4], breg[4];
  #pragma unroll
  for (int i = 0; i < 4; ++i) { areg[i] = agp[i]; breg[i] = bgp[i]; }

  for (int k0 = 0; k0 < Dd; k0 += BKF) {
    unsigned pa[8], pb[8];
    #pragma unroll
    for (int i = 0; i < 4; ++i) {
      sqa = fmaf(areg[i][0], areg[i][0], sqa); sqa = fmaf(areg[i][1], areg[i][1], sqa);
      sqa = fmaf(areg[i][2], areg[i][2], sqa); sqa = fmaf(areg[i][3], areg[i][3], sqa);
      pa[i*2+0] = pack2_bf16(areg[i][0], areg[i][1]); pa[i*2+1] = pack2_bf16(areg[i][2], areg[i][3]);
      sqb = fmaf(breg[i][0], breg[i][0], sqb); sqb = fmaf(breg[i][1], breg[i][1], sqb);
      sqb = fmaf(breg[i][2], breg[i][2], sqb); sqb = fmaf(breg[i][3], breg[i][3], sqb);
      pb[i*2+0] = pack2_bf16(breg[i][0], breg[i][1]); pb[i*2+1] = pack2_bf16(breg[i][2], breg[i][3]);
    }
    __syncthreads();
    awr[0] = (u32x4){pa[0],pa[1],pa[2],pa[3]}; awr[1] = (u32x4){pa[4],pa[5],pa[6],pa[7]};
    bwr[0] = (u32x4){pb[0],pb[1],pb[2],pb[3]}; bwr[1] = (u32x4){pb[4],pb[5],pb[6],pb[7]};
    __syncthreads();
    if (k0 + BKF < Dd) {
      const int off = (k0 + BKF) >> 2;
      #pragma unroll
      for (int i = 0; i < 4; ++i) { areg[i] = agp[off + i]; breg[i] = bgp[off + i]; }
    }
    s16x8 af[4], bfr[4];
    #pragma unroll
    for (int i = 0; i < 4; ++i) {
      af[i]  = *(const s16x8*)(As + (wm + i*16 + lm) * LDKF + kq * 8);
      bfr[i] = *(const s16x8*)(Bs + (wn + i*16 + lm) * LDKF + kq * 8);
    }
    #pragma unroll
    for (int mi = 0; mi < 4; ++mi)
      #pragma unroll
      for (int ni = 0; ni < 4; ++ni)
        acc[mi][ni] = __builtin_amdgcn_mfma_f32_16x16x32_bf16(af[mi], bfr[ni], acc[mi][ni], 0, 0, 0);
  }
  __syncthreads();
  ((float*)As)[t] = sqa; ((float*)Bs)[t] = sqb;
  __syncthreads();
  if (t < 128) {
    invA[t] = 1.0f / sqrtf(((float*)As)[2*t] + ((float*)As)[2*t+1]);
    invB[t] = 1.0f / sqrtf(((float*)Bs)[2*t] + ((float*)Bs)[2*t+1]);
  }
  __syncthreads();
  float* outb = out + (size_t)(b * Tt + tm * BM) * Ss + tn * BN;
  const int m0 = wm + kq * 4, n0 = wn + lm;
  #pragma unroll
  for (int mi = 0; mi < 4; ++mi) {
    #pragma unroll
    for (int r = 0; r < 4; ++r) {
      const int mrow = m0 + mi * 16 + r;
      const float ia = invA[mrow];
      float* orow = outb + (size_t)mrow * Ss;
      #pragma unroll
      for (int ni = 0; ni < 4; ++ni) {
        const int ncol = n0 + ni * 16;
        orow[ncol] = acc[mi][ni][r] * (ia * invB[ncol]);
      }
    }
  }
}

extern "C" void kernel_launch(void* const* d_in, const int* in_sizes, int n_in,
                              void* d_out, int out_size, void* d_ws, size_t ws_size,
                              hipStream_t stream) {
  const float* sup = (const float*)d_in[0];  // support_sets [8,1024,2048]
  const float* xh  = (const float*)d_in[1];  // X_hats       [8,1024,2048]
  float* out = (float*)d_out;                // [8,1024,1024] fp32

  const size_t nElem = (size_t)Bb * Tt * Dd;              // 16.78M per tensor
  const size_t bfBytes = nElem * sizeof(short);           // 33.55 MB
  const size_t NEED = 2 * bfBytes + 2 * (size_t)Bb * Tt * sizeof(float);

  if (ws_size >= NEED) {
    unsigned* abf = (unsigned*)d_ws;
    unsigned* bbf = (unsigned*)((char*)d_ws + bfBytes);
    float* invA = (float*)((char*)d_ws + 2 * bfBytes);
    float* invB = invA + (size_t)Bb * Tt;
    convertA_kernel<<<dim3(1024), dim3(256), 0, stream>>>(xh, abf, invA);
    convertB_kernel<<<dim3(8192), dim3(256), 0, stream>>>(sup, bbf, invB);
    gemm_kernel<<<dim3(512), dim3(256), 0, stream>>>((const short*)abf, (const short*)bbf,
                                                     invA, invB, out);
  } else {
    paircos_kernel<<<dim3(512), dim3(256), 0, stream>>>(sup, xh, out);
  }
}

// Round 4
// 193.067 us; speedup vs baseline: 1.0333x; 1.0333x over previous
//
#include <hip/hip_runtime.h>
#include <hip/hip_bf16.h>

typedef __attribute__((ext_vector_type(4))) float        f32x4;
typedef __attribute__((ext_vector_type(8))) short        s16x8;
typedef __attribute__((ext_vector_type(4))) unsigned int u32x4;
typedef __attribute__((ext_vector_type(2))) unsigned int u32x2;

#define Bb 8
#define Tt 1024
#define Ss 1024
#define Dd 2048
#define BM 128
#define BN 128
#define BK 64   // K-slab: 2 ks-steps of 32, 32 MFMA/wave/slab

// round-half-up f32 -> bf16, packed pair. Inputs are finite N(0,1); no NaN/Inf path.
__device__ __forceinline__ unsigned pack2_bf16(float f0, float f1) {
  unsigned u0 = __builtin_bit_cast(unsigned, f0) + 0x8000u;
  unsigned u1 = __builtin_bit_cast(unsigned, f1) + 0x8000u;
  return (u0 >> 16) | (u1 & 0xffff0000u);
}

// async global->LDS DMA, 16B/lane. LDS dest = wave-uniform base + lane*16.
__device__ __forceinline__ void gld_lds16(const void* g, void* l) {
  __builtin_amdgcn_global_load_lds(
      (__attribute__((address_space(1))) void*)(void*)(g),
      (__attribute__((address_space(3))) void*)l, 16, 0, 0);
}

// ---------------- Pass 1: fp32 -> bf16 convert + row inv-norm, one row/block ----
// r3 A/B verdict: hoist+fence arm == high-TLP arm (wall unchanged) -> convert is
// not per-wave-latency-bound; abandon that line. This variant unifies both
// tensors on the fully-coalesced pattern: loads s[t], s[256+t] (16B lane-contig),
// stores d[t], d[512+t] (8B lane-contig) — fixes convertB's stride-32B loads.
__global__ __launch_bounds__(256, 8)
void convert_kernel(const float* __restrict__ src, unsigned* __restrict__ dst,
                    float* __restrict__ inv)
{
  __shared__ float red[4];
  const int row = blockIdx.x;              // 8192 rows per tensor
  const int t = threadIdx.x;               // 0..255
  const f32x4* s = (const f32x4*)(src + (size_t)row * Dd);
  const f32x4 a = s[t];                    // elements [4t, 4t+4)
  const f32x4 b = s[256 + t];              // elements [1024+4t, 1024+4t+4)

  float sq = fmaf(a[0], a[0], fmaf(a[1], a[1], fmaf(a[2], a[2], a[3] * a[3])));
  sq = fmaf(b[0], b[0], fmaf(b[1], b[1], fmaf(b[2], b[2], fmaf(b[3], b[3], sq))));

  u32x2* d = (u32x2*)(dst + (size_t)row * (Dd / 2));
  d[t]       = (u32x2){pack2_bf16(a[0], a[1]), pack2_bf16(a[2], a[3])};
  d[256 + t] = (u32x2){pack2_bf16(b[0], b[1]), pack2_bf16(b[2], b[3])};

  #pragma unroll
  for (int m = 32; m; m >>= 1) sq += __shfl_xor(sq, m, 64);
  const int wave = t >> 6, lane = t & 63;
  if (lane == 0) red[wave] = sq;
  __syncthreads();
  if (t == 0) inv[row] = 1.0f / sqrtf(red[0] + red[1] + red[2] + red[3]);
}

// ---------------- Pass 2: bf16 GEMM, DMA staging, BK=64, counted-vmcnt pipeline ----
// v4 (T4): replace __syncthreads (implicit vmcnt(0) DRAIN of the just-issued
// prefetch) with raw s_barrier + s_waitcnt vmcnt(8): wait only for the slab we
// are about to read; the next slab's 8 DMAs stay in flight across the barrier.
// Correctness: vmcnt retires in order (m135); each wave's vmcnt(8) => its own
// 8 buffer-k DMAs landed; s_barrier => all waves' landed; STAGE into a buffer
// only after the barrier that ends that buffer's reads. Tail: last buffer gets
// an explicit vmcnt(0). Raw s_barrier inserts no auto-drain (m139).
// T1 XCD swizzle: grid=512=8*64 bijective, XCD x <- batch x.
// LDS tiles 128x64 bf16, x2 buffers = 64KB (2 blocks/CU). XOR swizzle on 16B chunks.
__global__ __launch_bounds__(256, 2)
void gemm_kernel(const short* __restrict__ abf, const short* __restrict__ bbf,
                 const float* __restrict__ invA, const float* __restrict__ invB,
                 float* __restrict__ out)
{
  __shared__ short As[2][BM * BK];   // 2 x 16 KB
  __shared__ short Bs[2][BN * BK];   // 2 x 16 KB

  const int bid0 = blockIdx.x;
  const int bid  = ((bid0 & 7) << 6) | (bid0 >> 3);   // T1: XCD-contiguous remap
  const int b    = bid >> 6;
  const int tile = bid & 63;
  const int tm   = tile >> 3;
  const int tn   = tile & 7;

  const int t = threadIdx.x, wave = t >> 6, lane = t & 63;

  const int srow = lane >> 3;
  const int cph  = lane & 7;
  const int r0   = wave * 32;

  const size_t aRow = (size_t)(b * Tt + tm * BM);
  const size_t bRow = (size_t)(b * Ss + tn * BN);
  const short *gA0, *gA1, *gA2, *gA3, *gB0, *gB1, *gB2, *gB3;
  {
    int r;
    r = r0 + 0 * 8 + srow; gA0 = abf + (aRow + r) * Dd + (cph ^ (r & 7)) * 8;
                           gB0 = bbf + (bRow + r) * Dd + (cph ^ (r & 7)) * 8;
    r = r0 + 1 * 8 + srow; gA1 = abf + (aRow + r) * Dd + (cph ^ (r & 7)) * 8;
                           gB1 = bbf + (bRow + r) * Dd + (cph ^ (r & 7)) * 8;
    r = r0 + 2 * 8 + srow; gA2 = abf + (aRow + r) * Dd + (cph ^ (r & 7)) * 8;
                           gB2 = bbf + (bRow + r) * Dd + (cph ^ (r & 7)) * 8;
    r = r0 + 3 * 8 + srow; gA3 = abf + (aRow + r) * Dd + (cph ^ (r & 7)) * 8;
                           gB3 = bbf + (bRow + r) * Dd + (cph ^ (r & 7)) * 8;
  }

  const int wm = (wave >> 1) << 6;
  const int wn = (wave & 1) << 6;
  const int lm = lane & 15;
  const int kq = lane >> 4;

  f32x4 acc[4][4];
  #pragma unroll
  for (int i = 0; i < 4; ++i)
    #pragma unroll
    for (int j = 0; j < 4; ++j)
      acc[i][j] = (f32x4)0.0f;

#define STAGE(bi) do {                                                   \
    gld_lds16(gA0, As[bi] + (r0 + 0)  * BK);                             \
    gld_lds16(gA1, As[bi] + (r0 + 8)  * BK);                             \
    gld_lds16(gA2, As[bi] + (r0 + 16) * BK);                             \
    gld_lds16(gA3, As[bi] + (r0 + 24) * BK);                             \
    gld_lds16(gB0, Bs[bi] + (r0 + 0)  * BK);                             \
    gld_lds16(gB1, Bs[bi] + (r0 + 8)  * BK);                             \
    gld_lds16(gB2, Bs[bi] + (r0 + 16) * BK);                             \
    gld_lds16(gB3, Bs[bi] + (r0 + 24) * BK);                             \
    gA0 += BK; gA1 += BK; gA2 += BK; gA3 += BK;                          \
    gB0 += BK; gB1 += BK; gB2 += BK; gB3 += BK;                          \
  } while (0)

#define COMPUTE(bi) do {                                                 \
    _Pragma("unroll")                                                    \
    for (int ks = 0; ks < 2; ++ks) {                                     \
      const int pchunk = ((ks * 4 + kq) ^ (lm & 7)) * 8;                 \
      s16x8 af[4], bfr[4];                                               \
      _Pragma("unroll")                                                  \
      for (int i = 0; i < 4; ++i) {                                      \
        af[i]  = *(const s16x8*)(As[bi] + (wm + i * 16 + lm) * BK + pchunk); \
        bfr[i] = *(const s16x8*)(Bs[bi] + (wn + i * 16 + lm) * BK + pchunk); \
      }                                                                  \
      _Pragma("unroll")                                                  \
      for (int mi = 0; mi < 4; ++mi)                                     \
        _Pragma("unroll")                                                \
        for (int ni = 0; ni < 4; ++ni)                                   \
          acc[mi][ni] = __builtin_amdgcn_mfma_f32_16x16x32_bf16(af[mi], bfr[ni], acc[mi][ni], 0, 0, 0); \
    }                                                                    \
  } while (0)

  // wait for this wave's oldest DMAs so only `n` remain outstanding, then join.
#define WAIT_BAR(n) do {                                                 \
    asm volatile("s_waitcnt vmcnt(" #n ")" ::: "memory");                \
    __builtin_amdgcn_s_barrier();                                        \
    __builtin_amdgcn_sched_barrier(0);                                   \
  } while (0)

  // prologue: slabs 0,1 in flight (16 outstanding)
  STAGE(0);
  STAGE(1);

  // steady: 15 iterations x 2 slabs = slabs 0..29; stages slabs 2..31.
  // Invariant at loop top: 16 outstanding (8 per buffer).
  for (int i = 0; i < 15; ++i) {
    WAIT_BAR(8);                   // buffer0 slab landed (8 newer still flying)
    COMPUTE(0);
    __builtin_amdgcn_sched_barrier(0);
    __builtin_amdgcn_s_barrier();  // all waves done reading buffer0
    STAGE(0);                      // slab 2i+2 -> 16 outstanding
    WAIT_BAR(8);                   // buffer1 slab landed
    COMPUTE(1);
    __builtin_amdgcn_sched_barrier(0);
    __builtin_amdgcn_s_barrier();  // all waves done reading buffer1
    STAGE(1);                      // slab 2i+3 -> 16 outstanding
  }

  // epilogue: slabs 30 (buffer0), 31 (buffer1); 16 outstanding on entry.
  WAIT_BAR(8);
  COMPUTE(0);
  WAIT_BAR(0);                     // final buffer needs a full wait
  COMPUTE(1);
#undef STAGE
#undef COMPUTE
#undef WAIT_BAR

  const float* iA = invA + b * Tt + tm * BM;
  const float* iB = invB + b * Ss + tn * BN;
  float* outb = out + (size_t)(b * Tt + tm * BM) * Ss + tn * BN;
  const int m0 = wm + kq * 4;
  const int n0 = wn + lm;
  #pragma unroll
  for (int mi = 0; mi < 4; ++mi) {
    #pragma unroll
    for (int r = 0; r < 4; ++r) {
      const int mrow = m0 + mi * 16 + r;
      const float ia = iA[mrow];
      float* orow = outb + (size_t)mrow * Ss;
      #pragma unroll
      for (int ni = 0; ni < 4; ++ni) {
        const int ncol = n0 + ni * 16;
        orow[ncol] = acc[mi][ni][r] * (ia * iB[ncol]);
      }
    }
  }
}

// ---------------- Fallback: round-1 fused kernel (used only if ws too small) ----------------
#define LDKF 40
#define BKF 32
__global__ __launch_bounds__(256, 2)
void paircos_kernel(const float* __restrict__ sup, const float* __restrict__ xh,
                    float* __restrict__ out)
{
  __shared__ short As[BM * LDKF];
  __shared__ short Bs[BN * LDKF];
  __shared__ float invA[BM];
  __shared__ float invB[BN];

  const int bid = blockIdx.x;
  const int b = bid >> 6, tile = bid & 63, tm = tile >> 3, tn = tile & 7;
  const float* Abase = xh  + (size_t)(b * Tt + tm * BM) * Dd;
  const float* Bbase = sup + (size_t)(b * Ss + tn * BN) * Dd;
  const int t = threadIdx.x, row = t >> 1, kh = t & 1;
  const f32x4* agp = (const f32x4*)(Abase + (size_t)row * Dd + kh * 16);
  const f32x4* bgp = (const f32x4*)(Bbase + (size_t)row * Dd + kh * 16);
  u32x4* awr = (u32x4*)(As + row * LDKF + kh * 16);
  u32x4* bwr = (u32x4*)(Bs + row * LDKF + kh * 16);
  const int wave = t >> 6, lane = t & 63;
  const int wm = (wave >> 1) << 6, wn = (wave & 1) << 6;
  const int lm = lane & 15, kq = lane >> 4;

  f32x4 acc[4][4];
  #pragma unroll
  for (int i = 0; i < 4; ++i)
    #pragma unroll
    for (int j = 0; j < 4; ++j) acc[i][j] = (f32x4)0.0f;
  float sqa = 0.0f, sqb = 0.0f;
  f32x4 areg[4], breg[4];
  #pragma unroll
  for (int i = 0; i < 4; ++i) { areg[i] = agp[i]; breg[i] = bgp[i]; }

  for (int k0 = 0; k0 < Dd; k0 += BKF) {
    unsigned pa[8], pb[8];
    #pragma unroll
    for (int i = 0; i < 4; ++i) {
      sqa = fmaf(areg[i][0], areg[i][0], sqa); sqa = fmaf(areg[i][1], areg[i][1], sqa);
      sqa = fmaf(areg[i][2], areg[i][2], sqa); sqa = fmaf(areg[i][3], areg[i][3], sqa);
      pa[i*2+0] = pack2_bf16(areg[i][0], areg[i][1]); pa[i*2+1] = pack2_bf16(areg[i][2], areg[i][3]);
      sqb = fmaf(breg[i][0], breg[i][0], sqb); sqb = fmaf(breg[i][1], breg[i][1], sqb);
      sqb = fmaf(breg[i][2], breg[i][2], sqb); sqb = fmaf(breg[i][3], breg[i][3], sqb);
      pb[i*2+0] = pack2_bf16(breg[i][0], breg[i][1]); pb[i*2+1] = pack2_bf16(breg[i][2], breg[i][3]);
    }
    __syncthreads();
    awr[0] = (u32x4){pa[0],pa[1],pa[2],pa[3]}; awr[1] = (u32x4){pa[4],pa[5],pa[6],pa[7]};
    bwr[0] = (u32x4){pb[0],pb[1],pb[2],pb[3]}; bwr[1] = (u32x4){pb[4],pb[5],pb[6],pb[7]};
    __syncthreads();
    if (k0 + BKF < Dd) {
      const int off = (k0 + BKF) >> 2;
      #pragma unroll
      for (int i = 0; i < 4; ++i) { areg[i] = agp[off + i]; breg[i] = bgp[off + i]; }
    }
    s16x8 af[4], bfr[4];
    #pragma unroll
    for (int i = 0; i < 4; ++i) {
      af[i]  = *(const s16x8*)(As + (wm + i*16 + lm) * LDKF + kq * 8);
      bfr[i] = *(const s16x8*)(Bs + (wn + i*16 + lm) * LDKF + kq * 8);
    }
    #pragma unroll
    for (int mi = 0; mi < 4; ++mi)
      #pragma unroll
      for (int ni = 0; ni < 4; ++ni)
        acc[mi][ni] = __builtin_amdgcn_mfma_f32_16x16x32_bf16(af[mi], bfr[ni], acc[mi][ni], 0, 0, 0);
  }
  __syncthreads();
  ((float*)As)[t] = sqa; ((float*)Bs)[t] = sqb;
  __syncthreads();
  if (t < 128) {
    invA[t] = 1.0f / sqrtf(((float*)As)[2*t] + ((float*)As)[2*t+1]);
    invB[t] = 1.0f / sqrtf(((float*)Bs)[2*t] + ((float*)Bs)[2*t+1]);
  }
  __syncthreads();
  float* outb = out + (size_t)(b * Tt + tm * BM) * Ss + tn * BN;
  const int m0 = wm + kq * 4, n0 = wn + lm;
  #pragma unroll
  for (int mi = 0; mi < 4; ++mi) {
    #pragma unroll
    for (int r = 0; r < 4; ++r) {
      const int mrow = m0 + mi * 16 + r;
      const float ia = invA[mrow];
      float* orow = outb + (size_t)mrow * Ss;
      #pragma unroll
      for (int ni = 0; ni < 4; ++ni) {
        const int ncol = n0 + ni * 16;
        orow[ncol] = acc[mi][ni][r] * (ia * invB[ncol]);
      }
    }
  }
}

extern "C" void kernel_launch(void* const* d_in, const int* in_sizes, int n_in,
                              void* d_out, int out_size, void* d_ws, size_t ws_size,
                              hipStream_t stream) {
  const float* sup = (const float*)d_in[0];  // support_sets [8,1024,2048]
  const float* xh  = (const float*)d_in[1];  // X_hats       [8,1024,2048]
  float* out = (float*)d_out;                // [8,1024,1024] fp32

  const size_t nElem = (size_t)Bb * Tt * Dd;              // 16.78M per tensor
  const size_t bfBytes = nElem * sizeof(short);           // 33.55 MB
  const size_t NEED = 2 * bfBytes + 2 * (size_t)Bb * Tt * sizeof(float);

  if (ws_size >= NEED) {
    unsigned* abf = (unsigned*)d_ws;
    unsigned* bbf = (unsigned*)((char*)d_ws + bfBytes);
    float* invA = (float*)((char*)d_ws + 2 * bfBytes);
    float* invB = invA + (size_t)Bb * Tt;
    convert_kernel<<<dim3(8192), dim3(256), 0, stream>>>(xh, abf, invA);
    convert_kernel<<<dim3(8192), dim3(256), 0, stream>>>(sup, bbf, invB);
    gemm_kernel<<<dim3(512), dim3(256), 0, stream>>>((const short*)abf, (const short*)bbf,
                                                     invA, invB, out);
  } else {
    paircos_kernel<<<dim3(512), dim3(256), 0, stream>>>(sup, xh, out);
  }
}